// Round 13
// baseline (1658.114 us; speedup 1.0000x reference)
//
#include <hip/hip_runtime.h>

#define V_IN 40962
#define V_OUT 163842
#define NCH 64
#define CTOT 256
#define NSLICE 8   // (b:2) x (channel-quarter:4); one slice per XCD via bid&7
#define CEXP 0.18033688011112042f   // log2(e)/8

typedef float    f2 __attribute__((ext_vector_type(2)));
typedef float    f4 __attribute__((ext_vector_type(4)));
typedef _Float16 h2 __attribute__((ext_vector_type(2)));
typedef _Float16 h4 __attribute__((ext_vector_type(4)));
typedef __fp16   hv2 __attribute__((ext_vector_type(2)));   // cvt_pkrtz / fdot2 operand type

#if defined(__has_builtin)
#if __has_builtin(__builtin_amdgcn_fdot2) && __has_builtin(__builtin_amdgcn_cvt_pkrtz)
#define USE_DOT2 1
#endif
#endif
#ifndef USE_DOT2
#define USE_DOT2 0
#endif

// ---------------- transpose+downcast + coeff prep (prescaled h2 e-pairs) ----------------
// scoefh[d*16 + ep*8 + f] = { C[(4ep+d)*8+f], C[(4ep+2+d)*8+f] } * CEXP   (fp16)
__global__ __launch_bounds__(256) void transpose_k(const float* __restrict__ x,
                                                   _Float16* __restrict__ xT,
                                                   const float* __restrict__ coeffs,
                                                   h2* __restrict__ scoefh) {
    if (blockIdx.x == 0 && blockIdx.y == 0 && blockIdx.z == 0 && threadIdx.x < 32) {
        const int m = threadIdx.x;
        const int f = m & 7, ep = (m >> 3) & 1, d = m >> 4;
        h2 v;
        v.x = (_Float16)(coeffs[(4 * ep + d) * 8 + f] * CEXP);
        v.y = (_Float16)(coeffs[(4 * ep + 2 + d) * 8 + f] * CEXP);
        scoefh[m] = v;
    }

    __shared__ float tile[64][65];   // [v][c]
    const int b  = blockIdx.z;
    const int v0 = blockIdx.x * 64;
    const int c0 = blockIdx.y * 64;
    const int t  = threadIdx.x;
    const int i  = t & 15;
    const int s  = t >> 4;           // 0..15
#pragma unroll
    for (int p = 0; p < 4; ++p) {
        int c = s + 16 * p;
        int v = 4 * i;
        f4 val = {0.f, 0.f, 0.f, 0.f};
        const float* src = x + ((size_t)b * CTOT + c0 + c) * V_IN + v0 + v;
        if (v0 + v + 3 < V_IN) {
            val = __builtin_nontemporal_load((const f4*)src);
        } else {
            if (v0 + v     < V_IN) val.x = src[0];
            if (v0 + v + 1 < V_IN) val.y = src[1];
            if (v0 + v + 2 < V_IN) val.z = src[2];
            if (v0 + v + 3 < V_IN) val.w = src[3];
        }
        tile[v    ][c] = val.x;
        tile[v + 1][c] = val.y;
        tile[v + 2][c] = val.z;
        tile[v + 3][c] = val.w;
    }
    __syncthreads();
#pragma unroll
    for (int p = 0; p < 4; ++p) {
        int v = s + 16 * p;
        if (v0 + v < V_IN) {
            h4 val;
            val.x = (_Float16)tile[v][4 * i];
            val.y = (_Float16)tile[v][4 * i + 1];
            val.z = (_Float16)tile[v][4 * i + 2];
            val.w = (_Float16)tile[v][4 * i + 3];
            *(h4*)(xT + ((size_t)b * V_IN + v0 + v) * CTOT + c0 + 4 * i) = val;
        }
    }
}

// ---------------- f32 fallback attention (cs2 scaled at load) ----------------
__device__ __forceinline__ float attn_one(const float vals[8], const f2 (&cs2)[8][4]) {
    f2 s2[4];
#pragma unroll
    for (int j = 0; j < 4; ++j) s2[j] = cs2[0][j] * vals[0];
#pragma unroll
    for (int k = 1; k < 8; ++k) {
        f2 vk = {vals[k], vals[k]};
#pragma unroll
        for (int j = 0; j < 4; ++j)
            s2[j] = __builtin_elementwise_fma(vk, cs2[k][j], s2[j]);
    }
    f2 sum2 = {0.f, 0.f}, num2 = {0.f, 0.f};
#pragma unroll
    for (int j = 0; j < 4; ++j) {
        f2 e;
        e.x = __builtin_amdgcn_exp2f(s2[j].x);
        e.y = __builtin_amdgcn_exp2f(s2[j].y);
        sum2 += e;
        f2 v2 = {vals[2 * j], vals[2 * j + 1]};
        num2 = __builtin_elementwise_fma(v2, e, num2);
    }
    return (num2.x + num2.y) * __builtin_amdgcn_rcpf(sum2.x + sum2.y);
}

__device__ __forceinline__ void unpack2(const h4& a0, const h4& a1, float (&vals)[8]) {
    vals[0] = (float)a0.x; vals[1] = (float)a1.x;
    vals[2] = (float)a0.y; vals[3] = (float)a1.y;
    vals[4] = (float)a0.z; vals[5] = (float)a1.z;
    vals[6] = (float)a0.w; vals[7] = (float)a1.w;
}

#if USE_DOT2
// Packed degree-4 poly for 2^x on [-1.05,1.05] (rel err ~1e-4; Chebyshev-economized).
__device__ __forceinline__ f2 exp2_poly(f2 x) {
    const f2 B4 = {0.009624f,  0.009624f};
    const f2 B3 = {0.0573327f, 0.0573327f};
    const f2 B2 = {0.240227f,  0.240227f};
    const f2 B1 = {0.692743f,  0.692743f};
    const f2 B0 = {1.0f, 1.0f};
    f2 p = __builtin_elementwise_fma(x, B4, B3);
    p = __builtin_elementwise_fma(x, p, B2);
    p = __builtin_elementwise_fma(x, p, B1);
    p = __builtin_elementwise_fma(x, p, B0);
    return p;
}

// ---------------- fp16-dot2 attention, e-pair layout: ZERO pack insts, no exp ----------------
// cs[d][ep][f] = {C[e=2ep][d][f], C[e=2ep+1][d][f]} * log2(e)/8.  p0 = row j0 (d=0), p1 = row j1 (d=1).
__device__ __forceinline__ float attn_dot2(const h4 p0, const h4 p1, const hv2 (&cs)[2][2][8]) {
    h2 l0; l0.x = p0.x; l0.y = p0.y; const hv2 a00 = __builtin_bit_cast(hv2, l0); // {e0,e1}@d0
    h2 l1; l1.x = p0.z; l1.y = p0.w; const hv2 a01 = __builtin_bit_cast(hv2, l1); // {e2,e3}@d0
    h2 l2; l2.x = p1.x; l2.y = p1.y; const hv2 a10 = __builtin_bit_cast(hv2, l2); // {e0,e1}@d1
    h2 l3; l3.x = p1.z; l3.y = p1.w; const hv2 a11 = __builtin_bit_cast(hv2, l3); // {e2,e3}@d1
    float s[8];
#pragma unroll
    for (int f = 0; f < 8; ++f) {
        float acc = __builtin_amdgcn_fdot2(a00, cs[0][0][f], 0.f, false);
        acc = __builtin_amdgcn_fdot2(a01, cs[0][1][f], acc, false);
        acc = __builtin_amdgcn_fdot2(a10, cs[1][0][f], acc, false);
        s[f] = __builtin_amdgcn_fdot2(a11, cs[1][1][f], acc, false);
    }
    // group s into e-pair order, poly-exp, pack to fp16 weights
    f2 t00 = {s[0], s[2]};   // f=2e+d: (e0,e1)@d0
    f2 t01 = {s[4], s[6]};   // (e2,e3)@d0
    f2 t10 = {s[1], s[3]};   // (e0,e1)@d1
    f2 t11 = {s[5], s[7]};   // (e2,e3)@d1
    f2 w00 = exp2_poly(t00), w01 = exp2_poly(t01), w10 = exp2_poly(t10), w11 = exp2_poly(t11);
    hv2 e00 = __builtin_amdgcn_cvt_pkrtz(w00.x, w00.y);
    hv2 e01 = __builtin_amdgcn_cvt_pkrtz(w01.x, w01.y);
    hv2 e10 = __builtin_amdgcn_cvt_pkrtz(w10.x, w10.y);
    hv2 e11 = __builtin_amdgcn_cvt_pkrtz(w11.x, w11.y);
    float num = __builtin_amdgcn_fdot2(a00, e00, 0.f, false);
    num = __builtin_amdgcn_fdot2(a01, e01, num, false);
    num = __builtin_amdgcn_fdot2(a10, e10, num, false);
    num = __builtin_amdgcn_fdot2(a11, e11, num, false);
    f2 sw = (w00 + w01) + (w10 + w11);
    float sum = sw.x + sw.y;
    return num * __builtin_amdgcn_rcpf(sum);
}
#endif

// ---------------- fused gather + attn + softmax + weighted sum ----------------
template <int DIRECT>
__global__ __launch_bounds__(256) void fused_k(const _Float16* __restrict__ xsrc16,
                                               const float* __restrict__ xsrc32,
                                               const void* __restrict__ csrc,
                                               const int* __restrict__ map,
                                               float* __restrict__ out) {
    __shared__ float otile[16][66];

    const int tid   = threadIdx.x;
    const int bid   = blockIdx.x;
    const int slice = bid & (NSLICE - 1);
    const int tile  = bid >> 3;
    const int vbase = tile * 64;
    const int b     = slice >> 2;
    const int c0    = (slice & 3) * 16;
    const bool full = (vbase + 64 <= V_OUT);

    const int cg = tid & 15;
    const int g  = tid >> 4;         // 0..15
    const int v0 = vbase + 4 * g;

#if USE_DOT2
    hv2 csh[2][2][8];
    if (!DIRECT) {
        const h2* ch = (const h2*)csrc;
#pragma unroll
        for (int d = 0; d < 2; ++d)
#pragma unroll
            for (int ep = 0; ep < 2; ++ep)
#pragma unroll
                for (int f = 0; f < 8; ++f)
                    csh[d][ep][f] = __builtin_bit_cast(hv2, ch[d * 16 + ep * 8 + f]);
    }
#endif
    f2 cs2[8][4];
    if (DIRECT) {
        const float* cf = (const float*)csrc;
#pragma unroll
        for (int k = 0; k < 8; ++k)
#pragma unroll
            for (int j = 0; j < 4; ++j) {
                f2 t = *(const f2*)(cf + k * 8 + 2 * j);
                cs2[k][j] = t * CEXP;
            }
    }

    const char* xs = (const char*)(xsrc16 + (size_t)b * V_IN * CTOT + 4 * c0);
    const unsigned cg8 = (unsigned)cg << 3;

    if (full && !DIRECT) {
        const int* mp = map + 2 * v0;
        int4 ja = *(const int4*)mp;
        int4 jb = *(const int4*)(mp + 4);
        h4 p0 = *(const h4*)(xs + (((unsigned)ja.x << 9) | cg8));
        h4 p1 = *(const h4*)(xs + (((unsigned)ja.y << 9) | cg8));
        h4 p2 = *(const h4*)(xs + (((unsigned)ja.z << 9) | cg8));
        h4 p3 = *(const h4*)(xs + (((unsigned)ja.w << 9) | cg8));
        h4 p4 = *(const h4*)(xs + (((unsigned)jb.x << 9) | cg8));
        h4 p5 = *(const h4*)(xs + (((unsigned)jb.y << 9) | cg8));
        h4 p6 = *(const h4*)(xs + (((unsigned)jb.z << 9) | cg8));
        h4 p7 = *(const h4*)(xs + (((unsigned)jb.w << 9) | cg8));
        float r0, r1, r2, r3;
#if USE_DOT2
        r0 = attn_dot2(p0, p1, csh);
        r1 = attn_dot2(p2, p3, csh);
        r2 = attn_dot2(p4, p5, csh);
        r3 = attn_dot2(p6, p7, csh);
#else
        r0 = r1 = r2 = r3 = 0.f;   // unreachable: !USE_DOT2 launches DIRECT only
#endif
        f2 w0 = {r0, r1}, w1 = {r2, r3};
        *(f2*)&otile[cg][4 * g]     = w0;
        *(f2*)&otile[cg][4 * g + 2] = w1;
    } else {
#pragma unroll
        for (int i = 0; i < 4; ++i) {
            const int v = v0 + i;
            float r = 0.f;
            if (v < V_OUT) {
                const int j0 = map[2 * v];
                const int j1 = map[2 * v + 1];
                if (DIRECT) {
                    float vals[8];
#pragma unroll
                    for (int e = 0; e < 4; ++e) {
                        vals[2 * e]     = xsrc32[((size_t)b * CTOT + (c0 + cg) * 4 + e) * V_IN + j0];
                        vals[2 * e + 1] = xsrc32[((size_t)b * CTOT + (c0 + cg) * 4 + e) * V_IN + j1];
                    }
                    r = attn_one(vals, cs2);
                } else {
                    h4 a0 = *(const h4*)(xs + (((unsigned)j0 << 9) | cg8));
                    h4 a1 = *(const h4*)(xs + (((unsigned)j1 << 9) | cg8));
#if USE_DOT2
                    r = attn_dot2(a0, a1, csh);
#else
                    r = 0.f;
#endif
                }
            }
            otile[cg][4 * g + i] = r;
        }
    }
    __syncthreads();

    // ---------------- write-out: 16 rows x 64 v, f2 NT stores (r9-r12 proven) ----------------
    if (full) {
#pragma unroll
        for (int it = 0; it < 2; ++it) {
            const int r = (tid >> 5) + 8 * it;   // 0..15
            const int q = tid & 31;              // v pair index
            f2 val = {otile[r][2 * q], otile[r][2 * q + 1]};
            __builtin_nontemporal_store(val,
                (f2*)(out + ((size_t)b * NCH + c0 + r) * V_OUT + vbase + 2 * q));
        }
    } else {
#pragma unroll
        for (int it = 0; it < 2; ++it) {
            const int r = (tid >> 5) + 8 * it;
            const int q = tid & 31;
#pragma unroll
            for (int u = 0; u < 2; ++u) {
                int v = vbase + 2 * q + u;
                if (v < V_OUT)
                    out[((size_t)b * NCH + c0 + r) * V_OUT + v] = otile[r][2 * q + u];
            }
        }
    }
}

extern "C" void kernel_launch(void* const* d_in, const int* in_sizes, int n_in,
                              void* d_out, int out_size, void* d_ws, size_t ws_size,
                              hipStream_t stream) {
    const float* x      = (const float*)d_in[0];
    const float* coeffs = (const float*)d_in[1];
    const int*   map    = (const int*)d_in[2];
    float*       out    = (float*)d_out;

    const size_t xT_bytes = (size_t)2 * V_IN * CTOT * sizeof(_Float16);
    const int ntiles  = (V_OUT + 63) / 64;
    const int nblocks = ntiles * NSLICE;

    if (USE_DOT2 && ws_size >= xT_bytes + 128) {
        _Float16* xT    = (_Float16*)d_ws;
        h2*       scoef = (h2*)((char*)d_ws + xT_bytes);
        dim3 tgrid((V_IN + 63) / 64, CTOT / 64, 2);
        transpose_k<<<tgrid, dim3(256), 0, stream>>>(x, xT, coeffs, scoef);
        fused_k<0><<<nblocks, 256, 0, stream>>>(xT, nullptr, scoef, map, out);
    } else {
        fused_k<1><<<nblocks, 256, 0, stream>>>(nullptr, x, coeffs, map, out);
    }
}

// Round 14
// 89.536 us; speedup vs baseline: 18.5191x; 18.5191x over previous
//
#include <hip/hip_runtime.h>

#define V_IN 40962
#define V_OUT 163842
#define NCH 64
#define CTOT 256
#define NSLICE 8   // (b:2) x (channel-quarter:4); one slice per XCD via bid&7
#define CEXP 0.18033688011112042f   // log2(e)/8

typedef float    f2 __attribute__((ext_vector_type(2)));
typedef float    f4 __attribute__((ext_vector_type(4)));
typedef _Float16 h2 __attribute__((ext_vector_type(2)));
typedef _Float16 h4 __attribute__((ext_vector_type(4)));
typedef __fp16   hv2 __attribute__((ext_vector_type(2)));   // cvt_pkrtz / fdot2 operand type

// Device-side only: gfx950 has both builtins (verified round 12: fused_k<0> dot2 path
// compiled, ran, and validated). Host pass lacks them -> NEVER use in host code.
#if defined(__HIP_DEVICE_COMPILE__) && defined(__has_builtin)
#if __has_builtin(__builtin_amdgcn_fdot2) && __has_builtin(__builtin_amdgcn_cvt_pkrtz)
#define USE_DOT2 1
#else
#define USE_DOT2 0
#endif
#else
#define USE_DOT2 0
#endif

// ---------------- transpose+downcast + coeff prep (prescaled h2 e-pairs) ----------------
// scoefh[d*16 + ep*8 + f] = { C[(4ep+d)*8+f], C[(4ep+2+d)*8+f] } * CEXP   (fp16)
__global__ __launch_bounds__(256) void transpose_k(const float* __restrict__ x,
                                                   _Float16* __restrict__ xT,
                                                   const float* __restrict__ coeffs,
                                                   h2* __restrict__ scoefh) {
    if (blockIdx.x == 0 && blockIdx.y == 0 && blockIdx.z == 0 && threadIdx.x < 32) {
        const int m = threadIdx.x;
        const int f = m & 7, ep = (m >> 3) & 1, d = m >> 4;
        h2 v;
        v.x = (_Float16)(coeffs[(4 * ep + d) * 8 + f] * CEXP);
        v.y = (_Float16)(coeffs[(4 * ep + 2 + d) * 8 + f] * CEXP);
        scoefh[m] = v;
    }

    __shared__ float tile[64][65];   // [v][c]
    const int b  = blockIdx.z;
    const int v0 = blockIdx.x * 64;
    const int c0 = blockIdx.y * 64;
    const int t  = threadIdx.x;
    const int i  = t & 15;
    const int s  = t >> 4;           // 0..15
#pragma unroll
    for (int p = 0; p < 4; ++p) {
        int c = s + 16 * p;
        int v = 4 * i;
        f4 val = {0.f, 0.f, 0.f, 0.f};
        const float* src = x + ((size_t)b * CTOT + c0 + c) * V_IN + v0 + v;
        if (v0 + v + 3 < V_IN) {
            val = __builtin_nontemporal_load((const f4*)src);
        } else {
            if (v0 + v     < V_IN) val.x = src[0];
            if (v0 + v + 1 < V_IN) val.y = src[1];
            if (v0 + v + 2 < V_IN) val.z = src[2];
            if (v0 + v + 3 < V_IN) val.w = src[3];
        }
        tile[v    ][c] = val.x;
        tile[v + 1][c] = val.y;
        tile[v + 2][c] = val.z;
        tile[v + 3][c] = val.w;
    }
    __syncthreads();
#pragma unroll
    for (int p = 0; p < 4; ++p) {
        int v = s + 16 * p;
        if (v0 + v < V_IN) {
            h4 val;
            val.x = (_Float16)tile[v][4 * i];
            val.y = (_Float16)tile[v][4 * i + 1];
            val.z = (_Float16)tile[v][4 * i + 2];
            val.w = (_Float16)tile[v][4 * i + 3];
            *(h4*)(xT + ((size_t)b * V_IN + v0 + v) * CTOT + c0 + 4 * i) = val;
        }
    }
}

// ---------------- f32 fallback attention (cs2 scaled at load) ----------------
__device__ __forceinline__ float attn_one(const float vals[8], const f2 (&cs2)[8][4]) {
    f2 s2[4];
#pragma unroll
    for (int j = 0; j < 4; ++j) s2[j] = cs2[0][j] * vals[0];
#pragma unroll
    for (int k = 1; k < 8; ++k) {
        f2 vk = {vals[k], vals[k]};
#pragma unroll
        for (int j = 0; j < 4; ++j)
            s2[j] = __builtin_elementwise_fma(vk, cs2[k][j], s2[j]);
    }
    f2 sum2 = {0.f, 0.f}, num2 = {0.f, 0.f};
#pragma unroll
    for (int j = 0; j < 4; ++j) {
        f2 e;
        e.x = __builtin_amdgcn_exp2f(s2[j].x);
        e.y = __builtin_amdgcn_exp2f(s2[j].y);
        sum2 += e;
        f2 v2 = {vals[2 * j], vals[2 * j + 1]};
        num2 = __builtin_elementwise_fma(v2, e, num2);
    }
    return (num2.x + num2.y) * __builtin_amdgcn_rcpf(sum2.x + sum2.y);
}

__device__ __forceinline__ void unpack2(const h4& a0, const h4& a1, float (&vals)[8]) {
    vals[0] = (float)a0.x; vals[1] = (float)a1.x;
    vals[2] = (float)a0.y; vals[3] = (float)a1.y;
    vals[4] = (float)a0.z; vals[5] = (float)a1.z;
    vals[6] = (float)a0.w; vals[7] = (float)a1.w;
}

#if USE_DOT2
// Packed degree-4 poly for 2^x on [-1.05,1.05] (rel err ~2e-4; minimax-fitted).
__device__ __forceinline__ f2 exp2_poly(f2 x) {
    const f2 B4 = {0.009624f,  0.009624f};
    const f2 B3 = {0.0573327f, 0.0573327f};
    const f2 B2 = {0.240227f,  0.240227f};
    const f2 B1 = {0.692743f,  0.692743f};
    const f2 B0 = {1.0f, 1.0f};
    f2 p = __builtin_elementwise_fma(x, B4, B3);
    p = __builtin_elementwise_fma(x, p, B2);
    p = __builtin_elementwise_fma(x, p, B1);
    p = __builtin_elementwise_fma(x, p, B0);
    return p;
}

// ---------------- fp16-dot2 attention, e-pair layout: ZERO pack insts, no exp ----------------
// cs[d][ep][f] = {C[e=2ep][d][f], C[e=2ep+1][d][f]} * log2(e)/8.  p0 = row j0 (d=0), p1 = row j1 (d=1).
// out = sum_{e,d} in[e,d] * softmax_f(s)[f=2e+d]
__device__ __forceinline__ float attn_dot2(const h4 p0, const h4 p1, const hv2 (&cs)[2][2][8]) {
    h2 l0; l0.x = p0.x; l0.y = p0.y; const hv2 a00 = __builtin_bit_cast(hv2, l0); // {e0,e1}@d0
    h2 l1; l1.x = p0.z; l1.y = p0.w; const hv2 a01 = __builtin_bit_cast(hv2, l1); // {e2,e3}@d0
    h2 l2; l2.x = p1.x; l2.y = p1.y; const hv2 a10 = __builtin_bit_cast(hv2, l2); // {e0,e1}@d1
    h2 l3; l3.x = p1.z; l3.y = p1.w; const hv2 a11 = __builtin_bit_cast(hv2, l3); // {e2,e3}@d1
    float s[8];
#pragma unroll
    for (int f = 0; f < 8; ++f) {
        float acc = __builtin_amdgcn_fdot2(a00, cs[0][0][f], 0.f, false);
        acc = __builtin_amdgcn_fdot2(a01, cs[0][1][f], acc, false);
        acc = __builtin_amdgcn_fdot2(a10, cs[1][0][f], acc, false);
        s[f] = __builtin_amdgcn_fdot2(a11, cs[1][1][f], acc, false);
    }
    // group s into e-pair order, poly-exp, pack to fp16 weights
    f2 t00 = {s[0], s[2]};   // f=2e+d: (e0,e1)@d0
    f2 t01 = {s[4], s[6]};   // (e2,e3)@d0
    f2 t10 = {s[1], s[3]};   // (e0,e1)@d1
    f2 t11 = {s[5], s[7]};   // (e2,e3)@d1
    f2 w00 = exp2_poly(t00), w01 = exp2_poly(t01), w10 = exp2_poly(t10), w11 = exp2_poly(t11);
    hv2 e00 = __builtin_amdgcn_cvt_pkrtz(w00.x, w00.y);
    hv2 e01 = __builtin_amdgcn_cvt_pkrtz(w01.x, w01.y);
    hv2 e10 = __builtin_amdgcn_cvt_pkrtz(w10.x, w10.y);
    hv2 e11 = __builtin_amdgcn_cvt_pkrtz(w11.x, w11.y);
    float num = __builtin_amdgcn_fdot2(a00, e00, 0.f, false);
    num = __builtin_amdgcn_fdot2(a01, e01, num, false);
    num = __builtin_amdgcn_fdot2(a10, e10, num, false);
    num = __builtin_amdgcn_fdot2(a11, e11, num, false);
    f2 sw = (w00 + w01) + (w10 + w11);
    float sum = sw.x + sw.y;
    return num * __builtin_amdgcn_rcpf(sum);
}
#endif

// ---------------- fused gather + attn + softmax + weighted sum ----------------
template <int DIRECT>
__global__ __launch_bounds__(256) void fused_k(const _Float16* __restrict__ xsrc16,
                                               const float* __restrict__ xsrc32,
                                               const void* __restrict__ csrc,
                                               const int* __restrict__ map,
                                               float* __restrict__ out) {
    __shared__ float otile[16][66];

    const int tid   = threadIdx.x;
    const int bid   = blockIdx.x;
    const int slice = bid & (NSLICE - 1);
    const int tile  = bid >> 3;
    const int vbase = tile * 64;
    const int b     = slice >> 2;
    const int c0    = (slice & 3) * 16;
    const bool full = (vbase + 64 <= V_OUT);

    const int cg = tid & 15;
    const int g  = tid >> 4;         // 0..15
    const int v0 = vbase + 4 * g;

#if USE_DOT2
    hv2 csh[2][2][8];
    if (!DIRECT) {
        const h2* ch = (const h2*)csrc;
#pragma unroll
        for (int d = 0; d < 2; ++d)
#pragma unroll
            for (int ep = 0; ep < 2; ++ep)
#pragma unroll
                for (int f = 0; f < 8; ++f)
                    csh[d][ep][f] = __builtin_bit_cast(hv2, ch[d * 16 + ep * 8 + f]);
    }
#endif
    f2 cs2[8][4];
    if (DIRECT) {
        const float* cf = (const float*)csrc;
#pragma unroll
        for (int k = 0; k < 8; ++k)
#pragma unroll
            for (int j = 0; j < 4; ++j) {
                f2 t = *(const f2*)(cf + k * 8 + 2 * j);
                cs2[k][j] = t * CEXP;
            }
    }

    const char* xs = (const char*)(xsrc16 + (size_t)b * V_IN * CTOT + 4 * c0);
    const unsigned cg8 = (unsigned)cg << 3;

    if (full && !DIRECT) {
        const int* mp = map + 2 * v0;
        int4 ja = *(const int4*)mp;
        int4 jb = *(const int4*)(mp + 4);
        h4 p0 = *(const h4*)(xs + (((unsigned)ja.x << 9) | cg8));
        h4 p1 = *(const h4*)(xs + (((unsigned)ja.y << 9) | cg8));
        h4 p2 = *(const h4*)(xs + (((unsigned)ja.z << 9) | cg8));
        h4 p3 = *(const h4*)(xs + (((unsigned)ja.w << 9) | cg8));
        h4 p4 = *(const h4*)(xs + (((unsigned)jb.x << 9) | cg8));
        h4 p5 = *(const h4*)(xs + (((unsigned)jb.y << 9) | cg8));
        h4 p6 = *(const h4*)(xs + (((unsigned)jb.z << 9) | cg8));
        h4 p7 = *(const h4*)(xs + (((unsigned)jb.w << 9) | cg8));
        float r0, r1, r2, r3;
#if USE_DOT2
        r0 = attn_dot2(p0, p1, csh);
        r1 = attn_dot2(p2, p3, csh);
        r2 = attn_dot2(p4, p5, csh);
        r3 = attn_dot2(p6, p7, csh);
#else
        float vals[8];
        f2 cfb[8][4];   // decode prescaled h2 e-pairs back to f32 k-layout
#pragma unroll
        for (int d = 0; d < 2; ++d)
#pragma unroll
            for (int ep = 0; ep < 2; ++ep)
#pragma unroll
                for (int f = 0; f < 8; ++f) {
                    h2 cv = ((const h2*)csrc)[d * 16 + ep * 8 + f];
                    cfb[(2 * ep) * 2 + d][f >> 1][f & 1]     = (float)cv.x;
                    cfb[(2 * ep + 1) * 2 + d][f >> 1][f & 1] = (float)cv.y;
                }
        unpack2(p0, p1, vals); r0 = attn_one(vals, cfb);
        unpack2(p2, p3, vals); r1 = attn_one(vals, cfb);
        unpack2(p4, p5, vals); r2 = attn_one(vals, cfb);
        unpack2(p6, p7, vals); r3 = attn_one(vals, cfb);
#endif
        f2 w0 = {r0, r1}, w1 = {r2, r3};
        *(f2*)&otile[cg][4 * g]     = w0;
        *(f2*)&otile[cg][4 * g + 2] = w1;
    } else {
#pragma unroll
        for (int i = 0; i < 4; ++i) {
            const int v = v0 + i;
            float r = 0.f;
            if (v < V_OUT) {
                const int j0 = map[2 * v];
                const int j1 = map[2 * v + 1];
                if (DIRECT) {
                    float vals[8];
#pragma unroll
                    for (int e = 0; e < 4; ++e) {
                        vals[2 * e]     = xsrc32[((size_t)b * CTOT + (c0 + cg) * 4 + e) * V_IN + j0];
                        vals[2 * e + 1] = xsrc32[((size_t)b * CTOT + (c0 + cg) * 4 + e) * V_IN + j1];
                    }
                    r = attn_one(vals, cs2);
                } else {
                    h4 a0 = *(const h4*)(xs + (((unsigned)j0 << 9) | cg8));
                    h4 a1 = *(const h4*)(xs + (((unsigned)j1 << 9) | cg8));
#if USE_DOT2
                    r = attn_dot2(a0, a1, csh);
#else
                    r = 0.f;   // non-full tail without dot2: covered by DIRECT launch path
#endif
                }
            }
            otile[cg][4 * g + i] = r;
        }
    }
    __syncthreads();

    // ---------------- write-out: 16 rows x 64 v, f2 NT stores (r9-r12 proven) ----------------
    if (full) {
#pragma unroll
        for (int it = 0; it < 2; ++it) {
            const int r = (tid >> 5) + 8 * it;   // 0..15
            const int q = tid & 31;              // v pair index
            f2 val = {otile[r][2 * q], otile[r][2 * q + 1]};
            __builtin_nontemporal_store(val,
                (f2*)(out + ((size_t)b * NCH + c0 + r) * V_OUT + vbase + 2 * q));
        }
    } else {
#pragma unroll
        for (int it = 0; it < 2; ++it) {
            const int r = (tid >> 5) + 8 * it;
            const int q = tid & 31;
#pragma unroll
            for (int u = 0; u < 2; ++u) {
                int v = vbase + 2 * q + u;
                if (v < V_OUT)
                    out[((size_t)b * NCH + c0 + r) * V_OUT + v] = otile[r][2 * q + u];
            }
        }
    }
}

extern "C" void kernel_launch(void* const* d_in, const int* in_sizes, int n_in,
                              void* d_out, int out_size, void* d_ws, size_t ws_size,
                              hipStream_t stream) {
    const float* x      = (const float*)d_in[0];
    const float* coeffs = (const float*)d_in[1];
    const int*   map    = (const int*)d_in[2];
    float*       out    = (float*)d_out;

    const size_t xT_bytes = (size_t)2 * V_IN * CTOT * sizeof(_Float16);
    const int ntiles  = (V_OUT + 63) / 64;
    const int nblocks = ntiles * NSLICE;

    // Host condition must NOT reference device builtins (r13 lesson): always
    // prefer the transposed path when workspace allows; device picks dot2.
    if (ws_size >= xT_bytes + 128) {
        _Float16* xT    = (_Float16*)d_ws;
        h2*       scoef = (h2*)((char*)d_ws + xT_bytes);
        dim3 tgrid((V_IN + 63) / 64, CTOT / 64, 2);
        transpose_k<<<tgrid, dim3(256), 0, stream>>>(x, xT, coeffs, scoef);
        fused_k<0><<<nblocks, 256, 0, stream>>>(xT, nullptr, scoef, map, out);
    } else {
        fused_k<1><<<nblocks, 256, 0, stream>>>(nullptr, x, coeffs, map, out);
    }
}

// Round 15
// 85.225 us; speedup vs baseline: 19.4558x; 1.0506x over previous
//
#include <hip/hip_runtime.h>

#define V_IN 40962
#define V_OUT 163842
#define NCH 64
#define CTOT 256
#define NSLICE 8   // (b:2) x (channel-quarter:4); one slice per XCD via bid&7
#define CEXP 0.18033688011112042f   // log2(e)/8

typedef float    f2 __attribute__((ext_vector_type(2)));
typedef float    f4 __attribute__((ext_vector_type(4)));
typedef _Float16 h2 __attribute__((ext_vector_type(2)));
typedef _Float16 h4 __attribute__((ext_vector_type(4)));
typedef __fp16   hv2 __attribute__((ext_vector_type(2)));   // cvt_pkrtz / fdot2 operand type

// Device-side only (r13 lesson: host pass lacks these builtins — never gate host code on them).
#if defined(__HIP_DEVICE_COMPILE__) && defined(__has_builtin)
#if __has_builtin(__builtin_amdgcn_fdot2) && __has_builtin(__builtin_amdgcn_cvt_pkrtz)
#define USE_DOT2 1
#else
#define USE_DOT2 0
#endif
#else
#define USE_DOT2 0
#endif

// ---------------- transpose+downcast + coeff prep (prescaled h2 e-pairs) ----------------
// scoefh[d*16 + ep*8 + f] = { C[(4ep+d)*8+f], C[(4ep+2+d)*8+f] } * CEXP   (fp16)
__global__ __launch_bounds__(256) void transpose_k(const float* __restrict__ x,
                                                   _Float16* __restrict__ xT,
                                                   const float* __restrict__ coeffs,
                                                   h2* __restrict__ scoefh) {
    if (blockIdx.x == 0 && blockIdx.y == 0 && blockIdx.z == 0 && threadIdx.x < 32) {
        const int m = threadIdx.x;
        const int f = m & 7, ep = (m >> 3) & 1, d = m >> 4;
        h2 v;
        v.x = (_Float16)(coeffs[(4 * ep + d) * 8 + f] * CEXP);
        v.y = (_Float16)(coeffs[(4 * ep + 2 + d) * 8 + f] * CEXP);
        scoefh[m] = v;
    }

    __shared__ float tile[64][65];   // [v][c]
    const int b  = blockIdx.z;
    const int v0 = blockIdx.x * 64;
    const int c0 = blockIdx.y * 64;
    const int t  = threadIdx.x;
    const int i  = t & 15;
    const int s  = t >> 4;           // 0..15
#pragma unroll
    for (int p = 0; p < 4; ++p) {
        int c = s + 16 * p;
        int v = 4 * i;
        f4 val = {0.f, 0.f, 0.f, 0.f};
        const float* src = x + ((size_t)b * CTOT + c0 + c) * V_IN + v0 + v;
        if (v0 + v + 3 < V_IN) {
            val = __builtin_nontemporal_load((const f4*)src);
        } else {
            if (v0 + v     < V_IN) val.x = src[0];
            if (v0 + v + 1 < V_IN) val.y = src[1];
            if (v0 + v + 2 < V_IN) val.z = src[2];
            if (v0 + v + 3 < V_IN) val.w = src[3];
        }
        tile[v    ][c] = val.x;
        tile[v + 1][c] = val.y;
        tile[v + 2][c] = val.z;
        tile[v + 3][c] = val.w;
    }
    __syncthreads();
#pragma unroll
    for (int p = 0; p < 4; ++p) {
        int v = s + 16 * p;
        if (v0 + v < V_IN) {
            h4 val;
            val.x = (_Float16)tile[v][4 * i];
            val.y = (_Float16)tile[v][4 * i + 1];
            val.z = (_Float16)tile[v][4 * i + 2];
            val.w = (_Float16)tile[v][4 * i + 3];
            *(h4*)(xT + ((size_t)b * V_IN + v0 + v) * CTOT + c0 + 4 * i) = val;
        }
    }
}

// ---------------- f32 fallback attention (cs2 scaled at load) ----------------
__device__ __forceinline__ float attn_one(const float vals[8], const f2 (&cs2)[8][4]) {
    f2 s2[4];
#pragma unroll
    for (int j = 0; j < 4; ++j) s2[j] = cs2[0][j] * vals[0];
#pragma unroll
    for (int k = 1; k < 8; ++k) {
        f2 vk = {vals[k], vals[k]};
#pragma unroll
        for (int j = 0; j < 4; ++j)
            s2[j] = __builtin_elementwise_fma(vk, cs2[k][j], s2[j]);
    }
    f2 sum2 = {0.f, 0.f}, num2 = {0.f, 0.f};
#pragma unroll
    for (int j = 0; j < 4; ++j) {
        f2 e;
        e.x = __builtin_amdgcn_exp2f(s2[j].x);
        e.y = __builtin_amdgcn_exp2f(s2[j].y);
        sum2 += e;
        f2 v2 = {vals[2 * j], vals[2 * j + 1]};
        num2 = __builtin_elementwise_fma(v2, e, num2);
    }
    return (num2.x + num2.y) * __builtin_amdgcn_rcpf(sum2.x + sum2.y);
}

__device__ __forceinline__ void unpack2(const h4& a0, const h4& a1, float (&vals)[8]) {
    vals[0] = (float)a0.x; vals[1] = (float)a1.x;
    vals[2] = (float)a0.y; vals[3] = (float)a1.y;
    vals[4] = (float)a0.z; vals[5] = (float)a1.z;
    vals[6] = (float)a0.w; vals[7] = (float)a1.w;
}

#if USE_DOT2
// Packed fp16 degree-4 poly for 2^x on [-1.05,1.05] -> guaranteed v_pk_fma_f16.
// rel err: poly 2e-4 + fp16 Horner rounding ~1.5e-3; softmax common-mode cancels most.
__device__ __forceinline__ hv2 exp2_poly_h(hv2 x) {
    const hv2 B4 = {(__fp16)0.009624f,  (__fp16)0.009624f};
    const hv2 B3 = {(__fp16)0.0573327f, (__fp16)0.0573327f};
    const hv2 B2 = {(__fp16)0.240227f,  (__fp16)0.240227f};
    const hv2 B1 = {(__fp16)0.692743f,  (__fp16)0.692743f};
    const hv2 B0 = {(__fp16)1.0f, (__fp16)1.0f};
    hv2 p = __builtin_elementwise_fma(x, B4, B3);
    p = __builtin_elementwise_fma(x, p, B2);
    p = __builtin_elementwise_fma(x, p, B1);
    p = __builtin_elementwise_fma(x, p, B0);
    return p;
}

// ---------------- fp16-dot2 attention, e-pair layout; poly in pk-f16 ----------------
// cs[d][ep][f] = {C[e=2ep][d][f], C[e=2ep+1][d][f]} * log2(e)/8.  p0 = row j0 (d=0), p1 = row j1 (d=1).
__device__ __forceinline__ float attn_dot2(const h4 p0, const h4 p1, const hv2 (&cs)[2][2][8]) {
    h2 l0; l0.x = p0.x; l0.y = p0.y; const hv2 a00 = __builtin_bit_cast(hv2, l0); // {e0,e1}@d0
    h2 l1; l1.x = p0.z; l1.y = p0.w; const hv2 a01 = __builtin_bit_cast(hv2, l1); // {e2,e3}@d0
    h2 l2; l2.x = p1.x; l2.y = p1.y; const hv2 a10 = __builtin_bit_cast(hv2, l2); // {e0,e1}@d1
    h2 l3; l3.x = p1.z; l3.y = p1.w; const hv2 a11 = __builtin_bit_cast(hv2, l3); // {e2,e3}@d1
    float s[8];
#pragma unroll
    for (int f = 0; f < 8; ++f) {
        float acc = __builtin_amdgcn_fdot2(a00, cs[0][0][f], 0.f, false);
        acc = __builtin_amdgcn_fdot2(a01, cs[0][1][f], acc, false);
        acc = __builtin_amdgcn_fdot2(a10, cs[1][0][f], acc, false);
        s[f] = __builtin_amdgcn_fdot2(a11, cs[1][1][f], acc, false);
    }
    // f = 2e+d: convert to fp16 in e-pair groups, poly-exp in pk-f16
    hv2 x00 = __builtin_amdgcn_cvt_pkrtz(s[0], s[2]);   // (e0,e1)@d0
    hv2 x01 = __builtin_amdgcn_cvt_pkrtz(s[4], s[6]);   // (e2,e3)@d0
    hv2 x10 = __builtin_amdgcn_cvt_pkrtz(s[1], s[3]);   // (e0,e1)@d1
    hv2 x11 = __builtin_amdgcn_cvt_pkrtz(s[5], s[7]);   // (e2,e3)@d1
    hv2 e00 = exp2_poly_h(x00);
    hv2 e01 = exp2_poly_h(x01);
    hv2 e10 = exp2_poly_h(x10);
    hv2 e11 = exp2_poly_h(x11);
    const hv2 ones = {(__fp16)1.0f, (__fp16)1.0f};
    float sum = __builtin_amdgcn_fdot2(e00, ones, 0.f, false);
    sum = __builtin_amdgcn_fdot2(e01, ones, sum, false);
    sum = __builtin_amdgcn_fdot2(e10, ones, sum, false);
    sum = __builtin_amdgcn_fdot2(e11, ones, sum, false);
    float num = __builtin_amdgcn_fdot2(a00, e00, 0.f, false);
    num = __builtin_amdgcn_fdot2(a01, e01, num, false);
    num = __builtin_amdgcn_fdot2(a10, e10, num, false);
    num = __builtin_amdgcn_fdot2(a11, e11, num, false);
    return num * __builtin_amdgcn_rcpf(sum);
}
#endif

// ---------------- fused gather + attn + softmax + weighted sum ----------------
template <int DIRECT>
__global__ __launch_bounds__(256) void fused_k(const _Float16* __restrict__ xsrc16,
                                               const float* __restrict__ xsrc32,
                                               const void* __restrict__ csrc,
                                               const int* __restrict__ map,
                                               float* __restrict__ out) {
    __shared__ float otile[16][66];

    const int tid   = threadIdx.x;
    const int bid   = blockIdx.x;
    const int slice = bid & (NSLICE - 1);
    const int tile  = bid >> 3;
    const int vbase = tile * 64;
    const int b     = slice >> 2;
    const int c0    = (slice & 3) * 16;
    const bool full = (vbase + 64 <= V_OUT);

    const int cg = tid & 15;
    const int g  = tid >> 4;         // 0..15
    const int v0 = vbase + 4 * g;

#if USE_DOT2
    hv2 csh[2][2][8];
    if (!DIRECT) {
        const h2* ch = (const h2*)csrc;
#pragma unroll
        for (int d = 0; d < 2; ++d)
#pragma unroll
            for (int ep = 0; ep < 2; ++ep)
#pragma unroll
                for (int f = 0; f < 8; ++f)
                    csh[d][ep][f] = __builtin_bit_cast(hv2, ch[d * 16 + ep * 8 + f]);
    }
#endif
    f2 cs2[8][4];
    if (DIRECT) {
        const float* cf = (const float*)csrc;
#pragma unroll
        for (int k = 0; k < 8; ++k)
#pragma unroll
            for (int j = 0; j < 4; ++j) {
                f2 t = *(const f2*)(cf + k * 8 + 2 * j);
                cs2[k][j] = t * CEXP;
            }
    }

    const char* xs = (const char*)(xsrc16 + (size_t)b * V_IN * CTOT + 4 * c0);
    const unsigned cg8 = (unsigned)cg << 3;

    if (full && !DIRECT) {
        const int* mp = map + 2 * v0;
        int4 ja = *(const int4*)mp;
        int4 jb = *(const int4*)(mp + 4);
        h4 p0 = *(const h4*)(xs + (((unsigned)ja.x << 9) | cg8));
        h4 p1 = *(const h4*)(xs + (((unsigned)ja.y << 9) | cg8));
        h4 p2 = *(const h4*)(xs + (((unsigned)ja.z << 9) | cg8));
        h4 p3 = *(const h4*)(xs + (((unsigned)ja.w << 9) | cg8));
        h4 p4 = *(const h4*)(xs + (((unsigned)jb.x << 9) | cg8));
        h4 p5 = *(const h4*)(xs + (((unsigned)jb.y << 9) | cg8));
        h4 p6 = *(const h4*)(xs + (((unsigned)jb.z << 9) | cg8));
        h4 p7 = *(const h4*)(xs + (((unsigned)jb.w << 9) | cg8));
        float r0, r1, r2, r3;
#if USE_DOT2
        r0 = attn_dot2(p0, p1, csh);
        r1 = attn_dot2(p2, p3, csh);
        r2 = attn_dot2(p4, p5, csh);
        r3 = attn_dot2(p6, p7, csh);
#else
        float vals[8];
        f2 cfb[8][4];   // decode prescaled h2 e-pairs back to f32 k-layout
#pragma unroll
        for (int d = 0; d < 2; ++d)
#pragma unroll
            for (int ep = 0; ep < 2; ++ep)
#pragma unroll
                for (int f = 0; f < 8; ++f) {
                    h2 cv = ((const h2*)csrc)[d * 16 + ep * 8 + f];
                    cfb[(2 * ep) * 2 + d][f >> 1][f & 1]     = (float)cv.x;
                    cfb[(2 * ep + 1) * 2 + d][f >> 1][f & 1] = (float)cv.y;
                }
        unpack2(p0, p1, vals); r0 = attn_one(vals, cfb);
        unpack2(p2, p3, vals); r1 = attn_one(vals, cfb);
        unpack2(p4, p5, vals); r2 = attn_one(vals, cfb);
        unpack2(p6, p7, vals); r3 = attn_one(vals, cfb);
#endif
        f2 w0 = {r0, r1}, w1 = {r2, r3};
        *(f2*)&otile[cg][4 * g]     = w0;
        *(f2*)&otile[cg][4 * g + 2] = w1;
    } else {
#pragma unroll
        for (int i = 0; i < 4; ++i) {
            const int v = v0 + i;
            float r = 0.f;
            if (v < V_OUT) {
                const int j0 = map[2 * v];
                const int j1 = map[2 * v + 1];
                if (DIRECT) {
                    float vals[8];
#pragma unroll
                    for (int e = 0; e < 4; ++e) {
                        vals[2 * e]     = xsrc32[((size_t)b * CTOT + (c0 + cg) * 4 + e) * V_IN + j0];
                        vals[2 * e + 1] = xsrc32[((size_t)b * CTOT + (c0 + cg) * 4 + e) * V_IN + j1];
                    }
                    r = attn_one(vals, cs2);
                } else {
                    h4 a0 = *(const h4*)(xs + (((unsigned)j0 << 9) | cg8));
                    h4 a1 = *(const h4*)(xs + (((unsigned)j1 << 9) | cg8));
#if USE_DOT2
                    r = attn_dot2(a0, a1, csh);
#else
                    r = 0.f;   // non-full tail without dot2: covered by DIRECT launch path
#endif
                }
            }
            otile[cg][4 * g + i] = r;
        }
    }
    __syncthreads();

    // ---------------- write-out: 16 rows x 64 v, f2 NT stores (r9-r14 proven) ----------------
    if (full) {
#pragma unroll
        for (int it = 0; it < 2; ++it) {
            const int r = (tid >> 5) + 8 * it;   // 0..15
            const int q = tid & 31;              // v pair index
            f2 val = {otile[r][2 * q], otile[r][2 * q + 1]};
            __builtin_nontemporal_store(val,
                (f2*)(out + ((size_t)b * NCH + c0 + r) * V_OUT + vbase + 2 * q));
        }
    } else {
#pragma unroll
        for (int it = 0; it < 2; ++it) {
            const int r = (tid >> 5) + 8 * it;
            const int q = tid & 31;
#pragma unroll
            for (int u = 0; u < 2; ++u) {
                int v = vbase + 2 * q + u;
                if (v < V_OUT)
                    out[((size_t)b * NCH + c0 + r) * V_OUT + v] = otile[r][2 * q + u];
            }
        }
    }
}

extern "C" void kernel_launch(void* const* d_in, const int* in_sizes, int n_in,
                              void* d_out, int out_size, void* d_ws, size_t ws_size,
                              hipStream_t stream) {
    const float* x      = (const float*)d_in[0];
    const float* coeffs = (const float*)d_in[1];
    const int*   map    = (const int*)d_in[2];
    float*       out    = (float*)d_out;

    const size_t xT_bytes = (size_t)2 * V_IN * CTOT * sizeof(_Float16);
    const int ntiles  = (V_OUT + 63) / 64;
    const int nblocks = ntiles * NSLICE;

    if (ws_size >= xT_bytes + 128) {
        _Float16* xT    = (_Float16*)d_ws;
        h2*       scoef = (h2*)((char*)d_ws + xT_bytes);
        dim3 tgrid((V_IN + 63) / 64, CTOT / 64, 2);
        transpose_k<<<tgrid, dim3(256), 0, stream>>>(x, xT, coeffs, scoef);
        fused_k<0><<<nblocks, 256, 0, stream>>>(xT, nullptr, scoef, map, out);
    } else {
        fused_k<1><<<nblocks, 256, 0, stream>>>(nullptr, x, coeffs, map, out);
    }
}

// Round 16
// 83.277 us; speedup vs baseline: 19.9107x; 1.0234x over previous
//
#include <hip/hip_runtime.h>

#define V_IN 40962
#define V_OUT 163842
#define NCH 64
#define CTOT 256
#define NSLICE 8   // (b:2) x (channel-quarter:4); one slice per XCD via bid&7
#define TILE_V 128
#define CEXP 0.18033688011112042f   // log2(e)/8

typedef float    f2 __attribute__((ext_vector_type(2)));
typedef float    f4 __attribute__((ext_vector_type(4)));
typedef _Float16 h2 __attribute__((ext_vector_type(2)));
typedef _Float16 h4 __attribute__((ext_vector_type(4)));
typedef __fp16   hv2 __attribute__((ext_vector_type(2)));

// Device-side only (r13 lesson: host pass lacks these builtins).
#if defined(__HIP_DEVICE_COMPILE__) && defined(__has_builtin)
#if __has_builtin(__builtin_amdgcn_fdot2) && __has_builtin(__builtin_amdgcn_cvt_pkrtz)
#define USE_DOT2 1
#else
#define USE_DOT2 0
#endif
#else
#define USE_DOT2 0
#endif

// ---------------- transpose+downcast + coeff prep (prescaled h2 e-pairs) ----------------
__global__ __launch_bounds__(256) void transpose_k(const float* __restrict__ x,
                                                   _Float16* __restrict__ xT,
                                                   const float* __restrict__ coeffs,
                                                   h2* __restrict__ scoefh) {
    if (blockIdx.x == 0 && blockIdx.y == 0 && blockIdx.z == 0 && threadIdx.x < 32) {
        const int m = threadIdx.x;
        const int f = m & 7, ep = (m >> 3) & 1, d = m >> 4;
        h2 v;
        v.x = (_Float16)(coeffs[(4 * ep + d) * 8 + f] * CEXP);
        v.y = (_Float16)(coeffs[(4 * ep + 2 + d) * 8 + f] * CEXP);
        scoefh[m] = v;
    }

    __shared__ float tile[64][65];
    const int b  = blockIdx.z;
    const int v0 = blockIdx.x * 64;
    const int c0 = blockIdx.y * 64;
    const int t  = threadIdx.x;
    const int i  = t & 15;
    const int s  = t >> 4;
#pragma unroll
    for (int p = 0; p < 4; ++p) {
        int c = s + 16 * p;
        int v = 4 * i;
        f4 val = {0.f, 0.f, 0.f, 0.f};
        const float* src = x + ((size_t)b * CTOT + c0 + c) * V_IN + v0 + v;
        if (v0 + v + 3 < V_IN) {
            val = __builtin_nontemporal_load((const f4*)src);
        } else {
            if (v0 + v     < V_IN) val.x = src[0];
            if (v0 + v + 1 < V_IN) val.y = src[1];
            if (v0 + v + 2 < V_IN) val.z = src[2];
            if (v0 + v + 3 < V_IN) val.w = src[3];
        }
        tile[v    ][c] = val.x;
        tile[v + 1][c] = val.y;
        tile[v + 2][c] = val.z;
        tile[v + 3][c] = val.w;
    }
    __syncthreads();
#pragma unroll
    for (int p = 0; p < 4; ++p) {
        int v = s + 16 * p;
        if (v0 + v < V_IN) {
            h4 val;
            val.x = (_Float16)tile[v][4 * i];
            val.y = (_Float16)tile[v][4 * i + 1];
            val.z = (_Float16)tile[v][4 * i + 2];
            val.w = (_Float16)tile[v][4 * i + 3];
            *(h4*)(xT + ((size_t)b * V_IN + v0 + v) * CTOT + c0 + 4 * i) = val;
        }
    }
}

// ---------------- f32 fallback attention ----------------
__device__ __forceinline__ float attn_one(const float vals[8], const f2 (&cs2)[8][4]) {
    f2 s2[4];
#pragma unroll
    for (int j = 0; j < 4; ++j) s2[j] = cs2[0][j] * vals[0];
#pragma unroll
    for (int k = 1; k < 8; ++k) {
        f2 vk = {vals[k], vals[k]};
#pragma unroll
        for (int j = 0; j < 4; ++j)
            s2[j] = __builtin_elementwise_fma(vk, cs2[k][j], s2[j]);
    }
    f2 sum2 = {0.f, 0.f}, num2 = {0.f, 0.f};
#pragma unroll
    for (int j = 0; j < 4; ++j) {
        f2 e;
        e.x = __builtin_amdgcn_exp2f(s2[j].x);
        e.y = __builtin_amdgcn_exp2f(s2[j].y);
        sum2 += e;
        f2 v2 = {vals[2 * j], vals[2 * j + 1]};
        num2 = __builtin_elementwise_fma(v2, e, num2);
    }
    return (num2.x + num2.y) * __builtin_amdgcn_rcpf(sum2.x + sum2.y);
}

__device__ __forceinline__ void unpack2(const h4& a0, const h4& a1, float (&vals)[8]) {
    vals[0] = (float)a0.x; vals[1] = (float)a1.x;
    vals[2] = (float)a0.y; vals[3] = (float)a1.y;
    vals[4] = (float)a0.z; vals[5] = (float)a1.z;
    vals[6] = (float)a0.w; vals[7] = (float)a1.w;
}

#if USE_DOT2
__device__ __forceinline__ hv2 exp2_poly_h(hv2 x) {
    const hv2 B4 = {(__fp16)0.009624f,  (__fp16)0.009624f};
    const hv2 B3 = {(__fp16)0.0573327f, (__fp16)0.0573327f};
    const hv2 B2 = {(__fp16)0.240227f,  (__fp16)0.240227f};
    const hv2 B1 = {(__fp16)0.692743f,  (__fp16)0.692743f};
    const hv2 B0 = {(__fp16)1.0f, (__fp16)1.0f};
    hv2 p = __builtin_elementwise_fma(x, B4, B3);
    p = __builtin_elementwise_fma(x, p, B2);
    p = __builtin_elementwise_fma(x, p, B1);
    p = __builtin_elementwise_fma(x, p, B0);
    return p;
}

__device__ __forceinline__ float attn_dot2(const h4 p0, const h4 p1, const hv2 (&cs)[2][2][8]) {
    h2 l0; l0.x = p0.x; l0.y = p0.y; const hv2 a00 = __builtin_bit_cast(hv2, l0);
    h2 l1; l1.x = p0.z; l1.y = p0.w; const hv2 a01 = __builtin_bit_cast(hv2, l1);
    h2 l2; l2.x = p1.x; l2.y = p1.y; const hv2 a10 = __builtin_bit_cast(hv2, l2);
    h2 l3; l3.x = p1.z; l3.y = p1.w; const hv2 a11 = __builtin_bit_cast(hv2, l3);
    float s[8];
#pragma unroll
    for (int f = 0; f < 8; ++f) {
        float acc = __builtin_amdgcn_fdot2(a00, cs[0][0][f], 0.f, false);
        acc = __builtin_amdgcn_fdot2(a01, cs[0][1][f], acc, false);
        acc = __builtin_amdgcn_fdot2(a10, cs[1][0][f], acc, false);
        s[f] = __builtin_amdgcn_fdot2(a11, cs[1][1][f], acc, false);
    }
    hv2 x00 = __builtin_amdgcn_cvt_pkrtz(s[0], s[2]);
    hv2 x01 = __builtin_amdgcn_cvt_pkrtz(s[4], s[6]);
    hv2 x10 = __builtin_amdgcn_cvt_pkrtz(s[1], s[3]);
    hv2 x11 = __builtin_amdgcn_cvt_pkrtz(s[5], s[7]);
    hv2 e00 = exp2_poly_h(x00);
    hv2 e01 = exp2_poly_h(x01);
    hv2 e10 = exp2_poly_h(x10);
    hv2 e11 = exp2_poly_h(x11);
    const hv2 ones = {(__fp16)1.0f, (__fp16)1.0f};
    float sum = __builtin_amdgcn_fdot2(e00, ones, 0.f, false);
    sum = __builtin_amdgcn_fdot2(e01, ones, sum, false);
    sum = __builtin_amdgcn_fdot2(e10, ones, sum, false);
    sum = __builtin_amdgcn_fdot2(e11, ones, sum, false);
    float num = __builtin_amdgcn_fdot2(a00, e00, 0.f, false);
    num = __builtin_amdgcn_fdot2(a01, e01, num, false);
    num = __builtin_amdgcn_fdot2(a10, e10, num, false);
    num = __builtin_amdgcn_fdot2(a11, e11, num, false);
    return num * __builtin_amdgcn_rcpf(sum);
}
#endif

// ---------------- fused: 128-v tile x one slice; 8 outputs / 16 gathers per thread ----------------
template <int DIRECT>
__global__ __launch_bounds__(256) void fused_k(const _Float16* __restrict__ xsrc16,
                                               const float* __restrict__ xsrc32,
                                               const void* __restrict__ csrc,
                                               const int* __restrict__ map,
                                               float* __restrict__ out) {
    __shared__ float otile[16][TILE_V + 2];

    const int tid   = threadIdx.x;
    const int bid   = blockIdx.x;
    const int slice = bid & (NSLICE - 1);
    const int tile  = bid >> 3;
    const int vbase = tile * TILE_V;
    const int b     = slice >> 2;
    const int c0    = (slice & 3) * 16;
    const bool full = (vbase + TILE_V <= V_OUT);

    const int cg = tid & 15;
    const int g  = tid >> 4;         // 0..15
    const int v0 = vbase + 8 * g;

#if USE_DOT2
    hv2 csh[2][2][8];
    if (!DIRECT) {
        const h2* ch = (const h2*)csrc;
#pragma unroll
        for (int d = 0; d < 2; ++d)
#pragma unroll
            for (int ep = 0; ep < 2; ++ep)
#pragma unroll
                for (int f = 0; f < 8; ++f)
                    csh[d][ep][f] = __builtin_bit_cast(hv2, ch[d * 16 + ep * 8 + f]);
    }
#endif
    f2 cs2[8][4];
    if (DIRECT) {
        const float* cf = (const float*)csrc;
#pragma unroll
        for (int k = 0; k < 8; ++k)
#pragma unroll
            for (int j = 0; j < 4; ++j) {
                f2 t = *(const f2*)(cf + k * 8 + 2 * j);
                cs2[k][j] = t * CEXP;
            }
    }

    const char* xs = (const char*)(xsrc16 + (size_t)b * V_IN * CTOT + 4 * c0);
    const unsigned cg8 = (unsigned)cg << 3;

    if (full && !DIRECT) {
#if USE_DOT2
        const int* mp = map + 2 * v0;
        int4 ja = *(const int4*)mp;
        int4 jb = *(const int4*)(mp + 4);
        int4 jc = *(const int4*)(mp + 8);
        int4 jd = *(const int4*)(mp + 12);
        // 16 gathers in flight before any compute
        h4 p0  = *(const h4*)(xs + (((unsigned)ja.x << 9) | cg8));
        h4 p1  = *(const h4*)(xs + (((unsigned)ja.y << 9) | cg8));
        h4 p2  = *(const h4*)(xs + (((unsigned)ja.z << 9) | cg8));
        h4 p3  = *(const h4*)(xs + (((unsigned)ja.w << 9) | cg8));
        h4 p4  = *(const h4*)(xs + (((unsigned)jb.x << 9) | cg8));
        h4 p5  = *(const h4*)(xs + (((unsigned)jb.y << 9) | cg8));
        h4 p6  = *(const h4*)(xs + (((unsigned)jb.z << 9) | cg8));
        h4 p7  = *(const h4*)(xs + (((unsigned)jb.w << 9) | cg8));
        h4 p8  = *(const h4*)(xs + (((unsigned)jc.x << 9) | cg8));
        h4 p9  = *(const h4*)(xs + (((unsigned)jc.y << 9) | cg8));
        h4 p10 = *(const h4*)(xs + (((unsigned)jc.z << 9) | cg8));
        h4 p11 = *(const h4*)(xs + (((unsigned)jc.w << 9) | cg8));
        h4 p12 = *(const h4*)(xs + (((unsigned)jd.x << 9) | cg8));
        h4 p13 = *(const h4*)(xs + (((unsigned)jd.y << 9) | cg8));
        h4 p14 = *(const h4*)(xs + (((unsigned)jd.z << 9) | cg8));
        h4 p15 = *(const h4*)(xs + (((unsigned)jd.w << 9) | cg8));
        float r0 = attn_dot2(p0,  p1,  csh);
        float r1 = attn_dot2(p2,  p3,  csh);
        float r2 = attn_dot2(p4,  p5,  csh);
        float r3 = attn_dot2(p6,  p7,  csh);
        float r4 = attn_dot2(p8,  p9,  csh);
        float r5 = attn_dot2(p10, p11, csh);
        float r6 = attn_dot2(p12, p13, csh);
        float r7 = attn_dot2(p14, p15, csh);
        f2 w0 = {r0, r1}, w1 = {r2, r3}, w2 = {r4, r5}, w3 = {r6, r7};
        *(f2*)&otile[cg][8 * g]     = w0;
        *(f2*)&otile[cg][8 * g + 2] = w1;
        *(f2*)&otile[cg][8 * g + 4] = w2;
        *(f2*)&otile[cg][8 * g + 6] = w3;
#endif
    } else {
#pragma unroll 2
        for (int i = 0; i < 8; ++i) {
            const int v = v0 + i;
            float r = 0.f;
            if (v < V_OUT) {
                const int j0 = map[2 * v];
                const int j1 = map[2 * v + 1];
                if (DIRECT) {
                    float vals[8];
#pragma unroll
                    for (int e = 0; e < 4; ++e) {
                        vals[2 * e]     = xsrc32[((size_t)b * CTOT + (c0 + cg) * 4 + e) * V_IN + j0];
                        vals[2 * e + 1] = xsrc32[((size_t)b * CTOT + (c0 + cg) * 4 + e) * V_IN + j1];
                    }
                    r = attn_one(vals, cs2);
                } else {
                    h4 a0 = *(const h4*)(xs + (((unsigned)j0 << 9) | cg8));
                    h4 a1 = *(const h4*)(xs + (((unsigned)j1 << 9) | cg8));
#if USE_DOT2
                    r = attn_dot2(a0, a1, csh);
#else
                    r = 0.f;
#endif
                }
            }
            otile[cg][8 * g + i] = r;
        }
    }
    __syncthreads();

    // ---------------- write-out: 16 rows x 128 v, f2 NT stores ----------------
    if (full) {
#pragma unroll
        for (int it = 0; it < 4; ++it) {
            const int idx = it * 256 + tid;
            const int r = idx >> 6;          // 0..15
            const int q = idx & 63;          // v-pair
            f2 val = {otile[r][2 * q], otile[r][2 * q + 1]};
            __builtin_nontemporal_store(val,
                (f2*)(out + ((size_t)b * NCH + c0 + r) * V_OUT + vbase + 2 * q));
        }
    } else {
#pragma unroll
        for (int it = 0; it < 4; ++it) {
            const int idx = it * 256 + tid;
            const int r = idx >> 6;
            const int q = idx & 63;
#pragma unroll
            for (int u = 0; u < 2; ++u) {
                int v = vbase + 2 * q + u;
                if (v < V_OUT)
                    out[((size_t)b * NCH + c0 + r) * V_OUT + v] = otile[r][2 * q + u];
            }
        }
    }
}

extern "C" void kernel_launch(void* const* d_in, const int* in_sizes, int n_in,
                              void* d_out, int out_size, void* d_ws, size_t ws_size,
                              hipStream_t stream) {
    const float* x      = (const float*)d_in[0];
    const float* coeffs = (const float*)d_in[1];
    const int*   map    = (const int*)d_in[2];
    float*       out    = (float*)d_out;

    const size_t xT_bytes = (size_t)2 * V_IN * CTOT * sizeof(_Float16);
    const int ntiles  = (V_OUT + TILE_V - 1) / TILE_V;
    const int nblocks = ntiles * NSLICE;

    if (ws_size >= xT_bytes + 128) {
        _Float16* xT    = (_Float16*)d_ws;
        h2*       scoef = (h2*)((char*)d_ws + xT_bytes);
        dim3 tgrid((V_IN + 63) / 64, CTOT / 64, 2);
        transpose_k<<<tgrid, dim3(256), 0, stream>>>(x, xT, coeffs, scoef);
        fused_k<0><<<nblocks, 256, 0, stream>>>(xT, nullptr, scoef, map, out);
    } else {
        fused_k<1><<<nblocks, 256, 0, stream>>>(nullptr, x, coeffs, map, out);
    }
}

// Round 17
// 76.911 us; speedup vs baseline: 21.5590x; 1.0828x over previous
//
#include <hip/hip_runtime.h>

#define V_IN 40962
#define V_OUT 163842
#define NCH 64
#define CTOT 256
#define NSLICE 8   // (b:2) x (channel-quarter:4); one slice per XCD via bid&7
#define TILE_V 128
#define CEXP 0.18033688011112042f   // log2(e)/8

typedef float    f2 __attribute__((ext_vector_type(2)));
typedef float    f4 __attribute__((ext_vector_type(4)));
typedef _Float16 h2 __attribute__((ext_vector_type(2)));
typedef _Float16 h4 __attribute__((ext_vector_type(4)));
typedef __fp16   hv2 __attribute__((ext_vector_type(2)));

// Device-side only (r13 lesson: host pass lacks these builtins).
#if defined(__HIP_DEVICE_COMPILE__) && defined(__has_builtin)
#if __has_builtin(__builtin_amdgcn_fdot2) && __has_builtin(__builtin_amdgcn_cvt_pkrtz)
#define USE_DOT2 1
#else
#define USE_DOT2 0
#endif
#else
#define USE_DOT2 0
#endif

// ---------------- transpose+downcast, SLICE-ALIGNED to XCD ----------------
// bid&7 = slice = (b, c-quarter): the same XCD that writes xT slice s (via its L2)
// runs the fused blocks that read slice s -> dirty-L2 reuse, no HBM round trip.
__global__ __launch_bounds__(256) void transpose_k(const float* __restrict__ x,
                                                   _Float16* __restrict__ xT,
                                                   const float* __restrict__ coeffs,
                                                   h2* __restrict__ scoefh) {
    const int bid   = blockIdx.x;
    if (bid == 0 && threadIdx.x < 32) {
        const int m = threadIdx.x;
        const int f = m & 7, ep = (m >> 3) & 1, d = m >> 4;
        h2 v;
        v.x = (_Float16)(coeffs[(4 * ep + d) * 8 + f] * CEXP);
        v.y = (_Float16)(coeffs[(4 * ep + 2 + d) * 8 + f] * CEXP);
        scoefh[m] = v;
    }

    const int slice = bid & (NSLICE - 1);
    const int b     = slice >> 2;
    const int c0    = (slice & 3) * 64;
    const int v0    = (bid >> 3) * 64;

    __shared__ float tile[64][65];   // [v][c]
    const int t = threadIdx.x;
    const int i = t & 15;
    const int s = t >> 4;            // 0..15
#pragma unroll
    for (int p = 0; p < 4; ++p) {
        int c = s + 16 * p;
        int v = 4 * i;
        f4 val = {0.f, 0.f, 0.f, 0.f};
        const float* src = x + ((size_t)b * CTOT + c0 + c) * V_IN + v0 + v;
        if (v0 + v + 3 < V_IN) {
            val = __builtin_nontemporal_load((const f4*)src);   // NT: don't evict xT lines
        } else {
            if (v0 + v     < V_IN) val.x = src[0];
            if (v0 + v + 1 < V_IN) val.y = src[1];
            if (v0 + v + 2 < V_IN) val.z = src[2];
            if (v0 + v + 3 < V_IN) val.w = src[3];
        }
        tile[v    ][c] = val.x;
        tile[v + 1][c] = val.y;
        tile[v + 2][c] = val.z;
        tile[v + 3][c] = val.w;
    }
    __syncthreads();
#pragma unroll
    for (int p = 0; p < 4; ++p) {
        int v = s + 16 * p;
        if (v0 + v < V_IN) {
            h4 val;
            val.x = (_Float16)tile[v][4 * i];
            val.y = (_Float16)tile[v][4 * i + 1];
            val.z = (_Float16)tile[v][4 * i + 2];
            val.w = (_Float16)tile[v][4 * i + 3];
            // regular store -> dirty line stays in this XCD's L2 for fused
            *(h4*)(xT + ((size_t)b * V_IN + v0 + v) * CTOT + c0 + 4 * i) = val;
        }
    }
}

// ---------------- f32 fallback attention ----------------
__device__ __forceinline__ float attn_one(const float vals[8], const f2 (&cs2)[8][4]) {
    f2 s2[4];
#pragma unroll
    for (int j = 0; j < 4; ++j) s2[j] = cs2[0][j] * vals[0];
#pragma unroll
    for (int k = 1; k < 8; ++k) {
        f2 vk = {vals[k], vals[k]};
#pragma unroll
        for (int j = 0; j < 4; ++j)
            s2[j] = __builtin_elementwise_fma(vk, cs2[k][j], s2[j]);
    }
    f2 sum2 = {0.f, 0.f}, num2 = {0.f, 0.f};
#pragma unroll
    for (int j = 0; j < 4; ++j) {
        f2 e;
        e.x = __builtin_amdgcn_exp2f(s2[j].x);
        e.y = __builtin_amdgcn_exp2f(s2[j].y);
        sum2 += e;
        f2 v2 = {vals[2 * j], vals[2 * j + 1]};
        num2 = __builtin_elementwise_fma(v2, e, num2);
    }
    return (num2.x + num2.y) * __builtin_amdgcn_rcpf(sum2.x + sum2.y);
}

__device__ __forceinline__ void unpack2(const h4& a0, const h4& a1, float (&vals)[8]) {
    vals[0] = (float)a0.x; vals[1] = (float)a1.x;
    vals[2] = (float)a0.y; vals[3] = (float)a1.y;
    vals[4] = (float)a0.z; vals[5] = (float)a1.z;
    vals[6] = (float)a0.w; vals[7] = (float)a1.w;
}

#if USE_DOT2
__device__ __forceinline__ hv2 exp2_poly_h(hv2 x) {
    const hv2 B4 = {(__fp16)0.009624f,  (__fp16)0.009624f};
    const hv2 B3 = {(__fp16)0.0573327f, (__fp16)0.0573327f};
    const hv2 B2 = {(__fp16)0.240227f,  (__fp16)0.240227f};
    const hv2 B1 = {(__fp16)0.692743f,  (__fp16)0.692743f};
    const hv2 B0 = {(__fp16)1.0f, (__fp16)1.0f};
    hv2 p = __builtin_elementwise_fma(x, B4, B3);
    p = __builtin_elementwise_fma(x, p, B2);
    p = __builtin_elementwise_fma(x, p, B1);
    p = __builtin_elementwise_fma(x, p, B0);
    return p;
}

__device__ __forceinline__ float attn_dot2(const h4 p0, const h4 p1, const hv2 (&cs)[2][2][8]) {
    h2 l0; l0.x = p0.x; l0.y = p0.y; const hv2 a00 = __builtin_bit_cast(hv2, l0);
    h2 l1; l1.x = p0.z; l1.y = p0.w; const hv2 a01 = __builtin_bit_cast(hv2, l1);
    h2 l2; l2.x = p1.x; l2.y = p1.y; const hv2 a10 = __builtin_bit_cast(hv2, l2);
    h2 l3; l3.x = p1.z; l3.y = p1.w; const hv2 a11 = __builtin_bit_cast(hv2, l3);
    float s[8];
#pragma unroll
    for (int f = 0; f < 8; ++f) {
        float acc = __builtin_amdgcn_fdot2(a00, cs[0][0][f], 0.f, false);
        acc = __builtin_amdgcn_fdot2(a01, cs[0][1][f], acc, false);
        acc = __builtin_amdgcn_fdot2(a10, cs[1][0][f], acc, false);
        s[f] = __builtin_amdgcn_fdot2(a11, cs[1][1][f], acc, false);
    }
    hv2 x00 = __builtin_amdgcn_cvt_pkrtz(s[0], s[2]);
    hv2 x01 = __builtin_amdgcn_cvt_pkrtz(s[4], s[6]);
    hv2 x10 = __builtin_amdgcn_cvt_pkrtz(s[1], s[3]);
    hv2 x11 = __builtin_amdgcn_cvt_pkrtz(s[5], s[7]);
    hv2 e00 = exp2_poly_h(x00);
    hv2 e01 = exp2_poly_h(x01);
    hv2 e10 = exp2_poly_h(x10);
    hv2 e11 = exp2_poly_h(x11);
    const hv2 ones = {(__fp16)1.0f, (__fp16)1.0f};
    float sum = __builtin_amdgcn_fdot2(e00, ones, 0.f, false);
    sum = __builtin_amdgcn_fdot2(e01, ones, sum, false);
    sum = __builtin_amdgcn_fdot2(e10, ones, sum, false);
    sum = __builtin_amdgcn_fdot2(e11, ones, sum, false);
    float num = __builtin_amdgcn_fdot2(a00, e00, 0.f, false);
    num = __builtin_amdgcn_fdot2(a01, e01, num, false);
    num = __builtin_amdgcn_fdot2(a10, e10, num, false);
    num = __builtin_amdgcn_fdot2(a11, e11, num, false);
    return num * __builtin_amdgcn_rcpf(sum);
}
#endif

// ---------------- fused: 128-v tile x one slice; 8 outputs / 16 gathers per thread ----------------
template <int DIRECT>
__global__ __launch_bounds__(256) void fused_k(const _Float16* __restrict__ xsrc16,
                                               const float* __restrict__ xsrc32,
                                               const void* __restrict__ csrc,
                                               const int* __restrict__ map,
                                               float* __restrict__ out) {
    __shared__ float otile[16][TILE_V + 2];

    const int tid   = threadIdx.x;
    const int bid   = blockIdx.x;
    const int slice = bid & (NSLICE - 1);
    const int tile  = bid >> 3;
    const int vbase = tile * TILE_V;
    const int b     = slice >> 2;
    const int c0    = (slice & 3) * 16;
    const bool full = (vbase + TILE_V <= V_OUT);

    const int cg = tid & 15;
    const int g  = tid >> 4;         // 0..15
    const int v0 = vbase + 8 * g;

#if USE_DOT2
    hv2 csh[2][2][8];
    if (!DIRECT) {
        const h2* ch = (const h2*)csrc;
#pragma unroll
        for (int d = 0; d < 2; ++d)
#pragma unroll
            for (int ep = 0; ep < 2; ++ep)
#pragma unroll
                for (int f = 0; f < 8; ++f)
                    csh[d][ep][f] = __builtin_bit_cast(hv2, ch[d * 16 + ep * 8 + f]);
    }
#endif
    f2 cs2[8][4];
    if (DIRECT) {
        const float* cf = (const float*)csrc;
#pragma unroll
        for (int k = 0; k < 8; ++k)
#pragma unroll
            for (int j = 0; j < 4; ++j) {
                f2 t = *(const f2*)(cf + k * 8 + 2 * j);
                cs2[k][j] = t * CEXP;
            }
    }

    const char* xs = (const char*)(xsrc16 + (size_t)b * V_IN * CTOT + 4 * c0);
    const unsigned cg8 = (unsigned)cg << 3;

    if (full && !DIRECT) {
#if USE_DOT2
        const int* mp = map + 2 * v0;
        int4 ja = *(const int4*)mp;
        int4 jb = *(const int4*)(mp + 4);
        int4 jc = *(const int4*)(mp + 8);
        int4 jd = *(const int4*)(mp + 12);
        // 16 gathers in flight before any compute
        h4 p0  = *(const h4*)(xs + (((unsigned)ja.x << 9) | cg8));
        h4 p1  = *(const h4*)(xs + (((unsigned)ja.y << 9) | cg8));
        h4 p2  = *(const h4*)(xs + (((unsigned)ja.z << 9) | cg8));
        h4 p3  = *(const h4*)(xs + (((unsigned)ja.w << 9) | cg8));
        h4 p4  = *(const h4*)(xs + (((unsigned)jb.x << 9) | cg8));
        h4 p5  = *(const h4*)(xs + (((unsigned)jb.y << 9) | cg8));
        h4 p6  = *(const h4*)(xs + (((unsigned)jb.z << 9) | cg8));
        h4 p7  = *(const h4*)(xs + (((unsigned)jb.w << 9) | cg8));
        h4 p8  = *(const h4*)(xs + (((unsigned)jc.x << 9) | cg8));
        h4 p9  = *(const h4*)(xs + (((unsigned)jc.y << 9) | cg8));
        h4 p10 = *(const h4*)(xs + (((unsigned)jc.z << 9) | cg8));
        h4 p11 = *(const h4*)(xs + (((unsigned)jc.w << 9) | cg8));
        h4 p12 = *(const h4*)(xs + (((unsigned)jd.x << 9) | cg8));
        h4 p13 = *(const h4*)(xs + (((unsigned)jd.y << 9) | cg8));
        h4 p14 = *(const h4*)(xs + (((unsigned)jd.z << 9) | cg8));
        h4 p15 = *(const h4*)(xs + (((unsigned)jd.w << 9) | cg8));
        float r0 = attn_dot2(p0,  p1,  csh);
        float r1 = attn_dot2(p2,  p3,  csh);
        float r2 = attn_dot2(p4,  p5,  csh);
        float r3 = attn_dot2(p6,  p7,  csh);
        float r4 = attn_dot2(p8,  p9,  csh);
        float r5 = attn_dot2(p10, p11, csh);
        float r6 = attn_dot2(p12, p13, csh);
        float r7 = attn_dot2(p14, p15, csh);
        f2 w0 = {r0, r1}, w1 = {r2, r3}, w2 = {r4, r5}, w3 = {r6, r7};
        *(f2*)&otile[cg][8 * g]     = w0;
        *(f2*)&otile[cg][8 * g + 2] = w1;
        *(f2*)&otile[cg][8 * g + 4] = w2;
        *(f2*)&otile[cg][8 * g + 6] = w3;
#endif
    } else {
#pragma unroll 2
        for (int i = 0; i < 8; ++i) {
            const int v = v0 + i;
            float r = 0.f;
            if (v < V_OUT) {
                const int j0 = map[2 * v];
                const int j1 = map[2 * v + 1];
                if (DIRECT) {
                    float vals[8];
#pragma unroll
                    for (int e = 0; e < 4; ++e) {
                        vals[2 * e]     = xsrc32[((size_t)b * CTOT + (c0 + cg) * 4 + e) * V_IN + j0];
                        vals[2 * e + 1] = xsrc32[((size_t)b * CTOT + (c0 + cg) * 4 + e) * V_IN + j1];
                    }
                    r = attn_one(vals, cs2);
                } else {
                    h4 a0 = *(const h4*)(xs + (((unsigned)j0 << 9) | cg8));
                    h4 a1 = *(const h4*)(xs + (((unsigned)j1 << 9) | cg8));
#if USE_DOT2
                    r = attn_dot2(a0, a1, csh);
#else
                    r = 0.f;
#endif
                }
            }
            otile[cg][8 * g + i] = r;
        }
    }
    __syncthreads();

    // ---------------- write-out: 16 rows x 128 v, f2 NT stores ----------------
    if (full) {
#pragma unroll
        for (int it = 0; it < 4; ++it) {
            const int idx = it * 256 + tid;
            const int r = idx >> 6;          // 0..15
            const int q = idx & 63;          // v-pair
            f2 val = {otile[r][2 * q], otile[r][2 * q + 1]};
            __builtin_nontemporal_store(val,
                (f2*)(out + ((size_t)b * NCH + c0 + r) * V_OUT + vbase + 2 * q));
        }
    } else {
#pragma unroll
        for (int it = 0; it < 4; ++it) {
            const int idx = it * 256 + tid;
            const int r = idx >> 6;
            const int q = idx & 63;
#pragma unroll
            for (int u = 0; u < 2; ++u) {
                int v = vbase + 2 * q + u;
                if (v < V_OUT)
                    out[((size_t)b * NCH + c0 + r) * V_OUT + v] = otile[r][2 * q + u];
            }
        }
    }
}

extern "C" void kernel_launch(void* const* d_in, const int* in_sizes, int n_in,
                              void* d_out, int out_size, void* d_ws, size_t ws_size,
                              hipStream_t stream) {
    const float* x      = (const float*)d_in[0];
    const float* coeffs = (const float*)d_in[1];
    const int*   map    = (const int*)d_in[2];
    float*       out    = (float*)d_out;

    const size_t xT_bytes = (size_t)2 * V_IN * CTOT * sizeof(_Float16);
    const int ntiles  = (V_OUT + TILE_V - 1) / TILE_V;
    const int nblocks = ntiles * NSLICE;
    const int tblocks = ((V_IN + 63) / 64) * NSLICE;   // slice-aligned 1D transpose grid

    if (ws_size >= xT_bytes + 128) {
        _Float16* xT    = (_Float16*)d_ws;
        h2*       scoef = (h2*)((char*)d_ws + xT_bytes);
        transpose_k<<<tblocks, 256, 0, stream>>>(x, xT, coeffs, scoef);
        fused_k<0><<<nblocks, 256, 0, stream>>>(xT, nullptr, scoef, map, out);
    } else {
        fused_k<1><<<nblocks, 256, 0, stream>>>(nullptr, x, coeffs, map, out);
    }
}

// Round 18
// 76.448 us; speedup vs baseline: 21.6893x; 1.0060x over previous
//
#include <hip/hip_runtime.h>

#define V_IN 40962
#define V_OUT 163842
#define NCH 64
#define CTOT 256
#define NSLICE 8   // (b:2) x (channel-quarter:4); one slice per XCD via bid&7
#define TILE_V 128
#define CEXP 0.18033688011112042f   // log2(e)/8

typedef float    f2 __attribute__((ext_vector_type(2)));
typedef float    f4 __attribute__((ext_vector_type(4)));
typedef _Float16 h2 __attribute__((ext_vector_type(2)));
typedef _Float16 h4 __attribute__((ext_vector_type(4)));
typedef _Float16 h8 __attribute__((ext_vector_type(8)));
typedef __fp16   hv2 __attribute__((ext_vector_type(2)));

// Device-side only (r13 lesson: host pass lacks these builtins).
#if defined(__HIP_DEVICE_COMPILE__) && defined(__has_builtin)
#if __has_builtin(__builtin_amdgcn_fdot2) && __has_builtin(__builtin_amdgcn_cvt_pkrtz)
#define USE_DOT2 1
#else
#define USE_DOT2 0
#endif
#else
#define USE_DOT2 0
#endif

// ---------------- transpose+downcast, SLICE-ALIGNED to XCD (r17-proven) ----------------
__global__ __launch_bounds__(256) void transpose_k(const float* __restrict__ x,
                                                   _Float16* __restrict__ xT,
                                                   const float* __restrict__ coeffs,
                                                   h2* __restrict__ scoefh) {
    const int bid = blockIdx.x;
    if (bid == 0 && threadIdx.x < 32) {
        const int m = threadIdx.x;
        const int f = m & 7, ep = (m >> 3) & 1, d = m >> 4;
        h2 v;
        v.x = (_Float16)(coeffs[(4 * ep + d) * 8 + f] * CEXP);
        v.y = (_Float16)(coeffs[(4 * ep + 2 + d) * 8 + f] * CEXP);
        scoefh[m] = v;
    }

    const int slice = bid & (NSLICE - 1);
    const int b     = slice >> 2;
    const int c0    = (slice & 3) * 64;
    const int v0    = (bid >> 3) * 64;

    __shared__ float tile[64][65];   // [v][c]
    const int t = threadIdx.x;
    const int i = t & 15;
    const int s = t >> 4;            // 0..15
#pragma unroll
    for (int p = 0; p < 4; ++p) {
        int c = s + 16 * p;
        int v = 4 * i;
        f4 val = {0.f, 0.f, 0.f, 0.f};
        const float* src = x + ((size_t)b * CTOT + c0 + c) * V_IN + v0 + v;
        if (v0 + v + 3 < V_IN) {
            val = __builtin_nontemporal_load((const f4*)src);
        } else {
            if (v0 + v     < V_IN) val.x = src[0];
            if (v0 + v + 1 < V_IN) val.y = src[1];
            if (v0 + v + 2 < V_IN) val.z = src[2];
            if (v0 + v + 3 < V_IN) val.w = src[3];
        }
        tile[v    ][c] = val.x;
        tile[v + 1][c] = val.y;
        tile[v + 2][c] = val.z;
        tile[v + 3][c] = val.w;
    }
    __syncthreads();
#pragma unroll
    for (int p = 0; p < 4; ++p) {
        int v = s + 16 * p;
        if (v0 + v < V_IN) {
            h4 val;
            val.x = (_Float16)tile[v][4 * i];
            val.y = (_Float16)tile[v][4 * i + 1];
            val.z = (_Float16)tile[v][4 * i + 2];
            val.w = (_Float16)tile[v][4 * i + 3];
            *(h4*)(xT + ((size_t)b * V_IN + v0 + v) * CTOT + c0 + 4 * i) = val;
        }
    }
}

// ---------------- f32 fallback attention ----------------
__device__ __forceinline__ float attn_one(const float vals[8], const f2 (&cs2)[8][4]) {
    f2 s2[4];
#pragma unroll
    for (int j = 0; j < 4; ++j) s2[j] = cs2[0][j] * vals[0];
#pragma unroll
    for (int k = 1; k < 8; ++k) {
        f2 vk = {vals[k], vals[k]};
#pragma unroll
        for (int j = 0; j < 4; ++j)
            s2[j] = __builtin_elementwise_fma(vk, cs2[k][j], s2[j]);
    }
    f2 sum2 = {0.f, 0.f}, num2 = {0.f, 0.f};
#pragma unroll
    for (int j = 0; j < 4; ++j) {
        f2 e;
        e.x = __builtin_amdgcn_exp2f(s2[j].x);
        e.y = __builtin_amdgcn_exp2f(s2[j].y);
        sum2 += e;
        f2 v2 = {vals[2 * j], vals[2 * j + 1]};
        num2 = __builtin_elementwise_fma(v2, e, num2);
    }
    return (num2.x + num2.y) * __builtin_amdgcn_rcpf(sum2.x + sum2.y);
}

#if USE_DOT2
__device__ __forceinline__ hv2 exp2_poly_h(hv2 x) {
    const hv2 B4 = {(__fp16)0.009624f,  (__fp16)0.009624f};
    const hv2 B3 = {(__fp16)0.0573327f, (__fp16)0.0573327f};
    const hv2 B2 = {(__fp16)0.240227f,  (__fp16)0.240227f};
    const hv2 B1 = {(__fp16)0.692743f,  (__fp16)0.692743f};
    const hv2 B0 = {(__fp16)1.0f, (__fp16)1.0f};
    hv2 p = __builtin_elementwise_fma(x, B4, B3);
    p = __builtin_elementwise_fma(x, p, B2);
    p = __builtin_elementwise_fma(x, p, B1);
    p = __builtin_elementwise_fma(x, p, B0);
    return p;
}

__device__ __forceinline__ float attn_dot2(const h4 p0, const h4 p1, const hv2 (&cs)[2][2][8]) {
    h2 l0; l0.x = p0.x; l0.y = p0.y; const hv2 a00 = __builtin_bit_cast(hv2, l0);
    h2 l1; l1.x = p0.z; l1.y = p0.w; const hv2 a01 = __builtin_bit_cast(hv2, l1);
    h2 l2; l2.x = p1.x; l2.y = p1.y; const hv2 a10 = __builtin_bit_cast(hv2, l2);
    h2 l3; l3.x = p1.z; l3.y = p1.w; const hv2 a11 = __builtin_bit_cast(hv2, l3);
    float s[8];
#pragma unroll
    for (int f = 0; f < 8; ++f) {
        float acc = __builtin_amdgcn_fdot2(a00, cs[0][0][f], 0.f, false);
        acc = __builtin_amdgcn_fdot2(a01, cs[0][1][f], acc, false);
        acc = __builtin_amdgcn_fdot2(a10, cs[1][0][f], acc, false);
        s[f] = __builtin_amdgcn_fdot2(a11, cs[1][1][f], acc, false);
    }
    hv2 x00 = __builtin_amdgcn_cvt_pkrtz(s[0], s[2]);
    hv2 x01 = __builtin_amdgcn_cvt_pkrtz(s[4], s[6]);
    hv2 x10 = __builtin_amdgcn_cvt_pkrtz(s[1], s[3]);
    hv2 x11 = __builtin_amdgcn_cvt_pkrtz(s[5], s[7]);
    hv2 e00 = exp2_poly_h(x00);
    hv2 e01 = exp2_poly_h(x01);
    hv2 e10 = exp2_poly_h(x10);
    hv2 e11 = exp2_poly_h(x11);
    const hv2 ones = {(__fp16)1.0f, (__fp16)1.0f};
    float sum = __builtin_amdgcn_fdot2(e00, ones, 0.f, false);
    sum = __builtin_amdgcn_fdot2(e01, ones, sum, false);
    sum = __builtin_amdgcn_fdot2(e10, ones, sum, false);
    sum = __builtin_amdgcn_fdot2(e11, ones, sum, false);
    float num = __builtin_amdgcn_fdot2(a00, e00, 0.f, false);
    num = __builtin_amdgcn_fdot2(a01, e01, num, false);
    num = __builtin_amdgcn_fdot2(a10, e10, num, false);
    num = __builtin_amdgcn_fdot2(a11, e11, num, false);
    return num * __builtin_amdgcn_rcpf(sum);
}

__device__ __forceinline__ h4 lo4(const h8 q) { h4 r; r.x = q.s0; r.y = q.s1; r.z = q.s2; r.w = q.s3; return r; }
__device__ __forceinline__ h4 hi4(const h8 q) { h4 r; r.x = q.s4; r.y = q.s5; r.z = q.s6; r.w = q.s7; return r; }
#endif

// ---------------- fused: 128-v tile x slice; h8 gathers -> 2 outputs per load-pair ----------------
// lane8 = tid&7 covers the 128B line in 8x16B; each thread computes cgroups {2*lane8, 2*lane8+1}.
// VMEM gathers per output: 1 (was 2).
template <int DIRECT>
__global__ __launch_bounds__(256) void fused_k(const _Float16* __restrict__ xsrc16,
                                               const float* __restrict__ xsrc32,
                                               const void* __restrict__ csrc,
                                               const int* __restrict__ map,
                                               float* __restrict__ out) {
    __shared__ float otile[16][TILE_V + 2];

    const int tid   = threadIdx.x;
    const int bid   = blockIdx.x;
    const int slice = bid & (NSLICE - 1);
    const int tile  = bid >> 3;
    const int vbase = tile * TILE_V;
    const int b     = slice >> 2;
    const int c0    = (slice & 3) * 16;     // cgroup base of this slice
    const bool full = (vbase + TILE_V <= V_OUT);

    const int lane8 = tid & 7;
    const int grp   = tid >> 3;             // 0..31
    const int v0    = vbase + 4 * grp;      // 4 vertices per thread

#if USE_DOT2
    hv2 csh[2][2][8];
    if (!DIRECT) {
        const h2* ch = (const h2*)csrc;
#pragma unroll
        for (int d = 0; d < 2; ++d)
#pragma unroll
            for (int ep = 0; ep < 2; ++ep)
#pragma unroll
                for (int f = 0; f < 8; ++f)
                    csh[d][ep][f] = __builtin_bit_cast(hv2, ch[d * 16 + ep * 8 + f]);
    }
#endif
    f2 cs2[8][4];
    if (DIRECT) {
        const float* cf = (const float*)csrc;
#pragma unroll
        for (int k = 0; k < 8; ++k)
#pragma unroll
            for (int j = 0; j < 4; ++j) {
                f2 t = *(const f2*)(cf + k * 8 + 2 * j);
                cs2[k][j] = t * CEXP;
            }
    }

    const char* xs = (const char*)(xsrc16 + (size_t)b * V_IN * CTOT + 4 * c0);
    const unsigned ln16 = (unsigned)lane8 << 4;
    const int row0 = 2 * lane8;

    if (full && !DIRECT) {
#if USE_DOT2
        const int* mp = map + 2 * v0;
        int4 ja = *(const int4*)mp;          // v0, v0+1
        int4 jb = *(const int4*)(mp + 4);    // v0+2, v0+3
        // 8 h8 gathers (one 16B load per vertex-row) in flight before any compute
        h8 q0 = *(const h8*)(xs + (((unsigned)ja.x << 9) | ln16));
        h8 q1 = *(const h8*)(xs + (((unsigned)ja.y << 9) | ln16));
        h8 q2 = *(const h8*)(xs + (((unsigned)ja.z << 9) | ln16));
        h8 q3 = *(const h8*)(xs + (((unsigned)ja.w << 9) | ln16));
        h8 q4 = *(const h8*)(xs + (((unsigned)jb.x << 9) | ln16));
        h8 q5 = *(const h8*)(xs + (((unsigned)jb.y << 9) | ln16));
        h8 q6 = *(const h8*)(xs + (((unsigned)jb.z << 9) | ln16));
        h8 q7 = *(const h8*)(xs + (((unsigned)jb.w << 9) | ln16));
        const int cb = 4 * grp;
        // v0+0
        otile[row0    ][cb]     = attn_dot2(lo4(q0), lo4(q1), csh);
        otile[row0 + 1][cb]     = attn_dot2(hi4(q0), hi4(q1), csh);
        // v0+1
        otile[row0    ][cb + 1] = attn_dot2(lo4(q2), lo4(q3), csh);
        otile[row0 + 1][cb + 1] = attn_dot2(hi4(q2), hi4(q3), csh);
        // v0+2
        otile[row0    ][cb + 2] = attn_dot2(lo4(q4), lo4(q5), csh);
        otile[row0 + 1][cb + 2] = attn_dot2(hi4(q4), hi4(q5), csh);
        // v0+3
        otile[row0    ][cb + 3] = attn_dot2(lo4(q6), lo4(q7), csh);
        otile[row0 + 1][cb + 3] = attn_dot2(hi4(q6), hi4(q7), csh);
#endif
    } else {
        for (int i = 0; i < 4; ++i) {
            const int v = v0 + i;
            float r0 = 0.f, r1 = 0.f;
            if (v < V_OUT) {
                const int j0 = map[2 * v];
                const int j1 = map[2 * v + 1];
                if (DIRECT) {
#pragma unroll
                    for (int sub = 0; sub < 2; ++sub) {
                        float vals[8];
#pragma unroll
                        for (int e = 0; e < 4; ++e) {
                            vals[2 * e]     = xsrc32[((size_t)b * CTOT + (c0 + row0 + sub) * 4 + e) * V_IN + j0];
                            vals[2 * e + 1] = xsrc32[((size_t)b * CTOT + (c0 + row0 + sub) * 4 + e) * V_IN + j1];
                        }
                        float rr = attn_one(vals, cs2);
                        if (sub == 0) r0 = rr; else r1 = rr;
                    }
                } else {
#if USE_DOT2
                    h8 a0 = *(const h8*)(xs + (((unsigned)j0 << 9) | ln16));
                    h8 a1 = *(const h8*)(xs + (((unsigned)j1 << 9) | ln16));
                    r0 = attn_dot2(lo4(a0), lo4(a1), csh);
                    r1 = attn_dot2(hi4(a0), hi4(a1), csh);
#endif
                }
            }
            otile[row0    ][4 * grp + i] = r0;
            otile[row0 + 1][4 * grp + i] = r1;
        }
    }
    __syncthreads();

    // ---------------- write-out: 16 rows x 128 v, f2 NT stores ----------------
    if (full) {
#pragma unroll
        for (int it = 0; it < 4; ++it) {
            const int idx = it * 256 + tid;
            const int r = idx >> 6;          // 0..15
            const int q = idx & 63;          // v-pair
            f2 val = {otile[r][2 * q], otile[r][2 * q + 1]};
            __builtin_nontemporal_store(val,
                (f2*)(out + ((size_t)b * NCH + c0 + r) * V_OUT + vbase + 2 * q));
        }
    } else {
#pragma unroll
        for (int it = 0; it < 4; ++it) {
            const int idx = it * 256 + tid;
            const int r = idx >> 6;
            const int q = idx & 63;
#pragma unroll
            for (int u = 0; u < 2; ++u) {
                int v = vbase + 2 * q + u;
                if (v < V_OUT)
                    out[((size_t)b * NCH + c0 + r) * V_OUT + v] = otile[r][2 * q + u];
            }
        }
    }
}

extern "C" void kernel_launch(void* const* d_in, const int* in_sizes, int n_in,
                              void* d_out, int out_size, void* d_ws, size_t ws_size,
                              hipStream_t stream) {
    const float* x      = (const float*)d_in[0];
    const float* coeffs = (const float*)d_in[1];
    const int*   map    = (const int*)d_in[2];
    float*       out    = (float*)d_out;

    const size_t xT_bytes = (size_t)2 * V_IN * CTOT * sizeof(_Float16);
    const int ntiles  = (V_OUT + TILE_V - 1) / TILE_V;
    const int nblocks = ntiles * NSLICE;
    const int tblocks = ((V_IN + 63) / 64) * NSLICE;

    if (ws_size >= xT_bytes + 128) {
        _Float16* xT    = (_Float16*)d_ws;
        h2*       scoef = (h2*)((char*)d_ws + xT_bytes);
        transpose_k<<<tblocks, 256, 0, stream>>>(x, xT, coeffs, scoef);
        fused_k<0><<<nblocks, 256, 0, stream>>>(xT, nullptr, scoef, map, out);
    } else {
        fused_k<1><<<nblocks, 256, 0, stream>>>(nullptr, x, coeffs, map, out);
    }
}